// Round 6
// baseline (3681.187 us; speedup 1.0000x reference)
//
#include <hip/hip_runtime.h>
#include <hip/hip_bf16.h>

// ---------------------------------------------------------------------------
// CNNMambaFast fp32 pipeline for MI355X.
// Shapes: B=4, T=512, mel=80 -> flux 160 -> CNN -> seq [4,512,960]
// 3 Mamba layers (D_INNER=1920, N=16, DT_RANK=60, D_CONV=4) -> fc 10 classes.
// ---------------------------------------------------------------------------

#define B_ 4
#define T_ 512
#define DM 960
#define DI 1920
#define NST 16
#define DTR 60

// ---------------- flux: [4,80,512] -> h0 [4,160,512] ------------------------
__global__ __launch_bounds__(256) void k_flux(const float* __restrict__ x,
                                              float* __restrict__ h0) {
  int idx = blockIdx.x * 256 + threadIdx.x;      // over 4*160*512
  int t = idx & 511;
  int f = (idx >> 9) % 160;
  int b = idx / (160 * 512);
  float v;
  if (f < 80) {
    v = x[(size_t)(b * 80 + f) * 512 + t];
  } else {
    int fm = f - 80;
    v = (t == 0) ? 0.f
                 : fmaxf(x[(size_t)(b * 80 + fm) * 512 + t] -
                         x[(size_t)(b * 80 + fm) * 512 + t - 1], 0.f);
  }
  h0[idx] = v;
}

// ---------------- RB1 conv1 (1->24, 3x3, relu), channels-last out -----------
__global__ __launch_bounds__(256) void k_rb1_conv1(const float* __restrict__ h0,
                                                   const float* __restrict__ w1,
                                                   const float* __restrict__ b1,
                                                   float* __restrict__ o1) {
  __shared__ __align__(16) float wT[9][24];
  __shared__ float bb[24];
  int tid = threadIdx.x;
  if (tid < 216) wT[tid % 9][tid / 9] = w1[tid];
  if (tid >= 216 && tid < 240) bb[tid - 216] = b1[tid - 216];
  __syncthreads();
  int idx = blockIdx.x * 256 + tid;              // (b,f,t) over 4*160*512
  int t = idx & 511;
  int f = (idx >> 9) % 160;
  int b = idx / (160 * 512);
  float acc[24];
#pragma unroll
  for (int c = 0; c < 24; ++c) acc[c] = bb[c];
#pragma unroll
  for (int i = 0; i < 3; ++i) {
    int fi = f - 1 + i;
    if (fi < 0 || fi >= 160) continue;
#pragma unroll
    for (int j = 0; j < 3; ++j) {
      int tj = t - 1 + j;
      if (tj < 0 || tj >= 512) continue;
      float v = h0[((size_t)(b * 160 + fi) << 9) + tj];
      const float4* wr = (const float4*)&wT[i * 3 + j][0];
#pragma unroll
      for (int q = 0; q < 6; ++q) {
        float4 wv = wr[q];
        acc[q * 4 + 0] += wv.x * v; acc[q * 4 + 1] += wv.y * v;
        acc[q * 4 + 2] += wv.z * v; acc[q * 4 + 3] += wv.w * v;
      }
    }
  }
  float* dst = o1 + (size_t)idx * 24;
#pragma unroll
  for (int q = 0; q < 6; ++q) {
    float4 o;
    o.x = fmaxf(acc[q * 4 + 0], 0.f); o.y = fmaxf(acc[q * 4 + 1], 0.f);
    o.z = fmaxf(acc[q * 4 + 2], 0.f); o.w = fmaxf(acc[q * 4 + 3], 0.f);
    *(float4*)(dst + q * 4) = o;
  }
}

// ------------- RB1 conv2 + 1x1 skip + relu + maxpool(2,1) -------------------
__global__ __launch_bounds__(256) void k_rb1_rest(const float* __restrict__ o1,
                                                  const float* __restrict__ h0,
                                                  const float* __restrict__ w2,
                                                  const float* __restrict__ b2,
                                                  const float* __restrict__ wsk,
                                                  const float* __restrict__ bsk,
                                                  float* __restrict__ p1) {
  __shared__ __align__(16) float wT2[5184];   // [ci][ij][c]
  __shared__ float bb[24], wss[24], bss[24];
  int tid = threadIdx.x;
  for (int l = tid; l < 5184; l += 256) {
    int c = l / 216, r = l % 216;
    wT2[r * 24 + c] = w2[l];
  }
  if (tid < 24) { bb[tid] = b2[tid]; wss[tid] = wsk[tid]; bss[tid] = bsk[tid]; }
  __syncthreads();
  int idx = blockIdx.x * 256 + tid;              // (b,f2,t) over 4*80*512
  int t = idx & 511;
  int f2 = (idx >> 9) % 80;
  int b = idx / (80 * 512);
  float acc0[24], acc1[24];
#pragma unroll
  for (int c = 0; c < 24; ++c) { acc0[c] = bb[c]; acc1[c] = bb[c]; }
  for (int fr = 0; fr < 4; ++fr) {
    int fi = 2 * f2 - 1 + fr;
    bool fok = (fi >= 0 && fi < 160);
    for (int jr = 0; jr < 3; ++jr) {
      int tj = t - 1 + jr;
      bool ok = fok && (tj >= 0) && (tj < 512);
      float in_[24];
      if (ok) {
        const float4* src = (const float4*)(o1 + ((size_t)(b * 160 + fi) * 512 + tj) * 24);
#pragma unroll
        for (int q = 0; q < 6; ++q) {
          float4 v = src[q];
          in_[q * 4] = v.x; in_[q * 4 + 1] = v.y; in_[q * 4 + 2] = v.z; in_[q * 4 + 3] = v.w;
        }
      } else {
#pragma unroll
        for (int q = 0; q < 24; ++q) in_[q] = 0.f;
      }
      if (fr < 3) {
        int ij = fr * 3 + jr;
#pragma unroll
        for (int ci = 0; ci < 24; ++ci) {
          float iv = in_[ci];
          const float4* wr = (const float4*)&wT2[(ci * 9 + ij) * 24];
#pragma unroll
          for (int q = 0; q < 6; ++q) {
            float4 wv = wr[q];
            acc0[q * 4 + 0] += wv.x * iv; acc0[q * 4 + 1] += wv.y * iv;
            acc0[q * 4 + 2] += wv.z * iv; acc0[q * 4 + 3] += wv.w * iv;
          }
        }
      }
      if (fr >= 1) {
        int ij = (fr - 1) * 3 + jr;
#pragma unroll
        for (int ci = 0; ci < 24; ++ci) {
          float iv = in_[ci];
          const float4* wr = (const float4*)&wT2[(ci * 9 + ij) * 24];
#pragma unroll
          for (int q = 0; q < 6; ++q) {
            float4 wv = wr[q];
            acc1[q * 4 + 0] += wv.x * iv; acc1[q * 4 + 1] += wv.y * iv;
            acc1[q * 4 + 2] += wv.z * iv; acc1[q * 4 + 3] += wv.w * iv;
          }
        }
      }
    }
  }
  float h0a = h0[((size_t)(b * 160 + 2 * f2) << 9) + t];
  float h0b = h0[((size_t)(b * 160 + 2 * f2 + 1) << 9) + t];
  float* dst = p1 + (size_t)idx * 24;
#pragma unroll
  for (int q = 0; q < 6; ++q) {
    float4 o;
#pragma unroll
    for (int e = 0; e < 4; ++e) {
      int c = q * 4 + e;
      float v0 = fmaxf(acc0[c] + wss[c] * h0a + bss[c], 0.f);
      float v1 = fmaxf(acc1[c] + wss[c] * h0b + bss[c], 0.f);
      ((float*)&o)[e] = fmaxf(v0, v1);
    }
    *(float4*)(dst + q * 4) = o;
  }
}

// ---------------- RB2 conv1 (24->24, 3x3, relu) -----------------------------
__global__ __launch_bounds__(256) void k_rb2_conv1(const float* __restrict__ p1,
                                                   const float* __restrict__ w,
                                                   const float* __restrict__ bias,
                                                   float* __restrict__ o2) {
  __shared__ __align__(16) float wT[5184];
  __shared__ float bb[24];
  int tid = threadIdx.x;
  for (int l = tid; l < 5184; l += 256) {
    int c = l / 216, r = l % 216;
    wT[r * 24 + c] = w[l];
  }
  if (tid < 24) bb[tid] = bias[tid];
  __syncthreads();
  int idx = blockIdx.x * 256 + tid;              // (b,f,t) over 4*80*512
  int t = idx & 511;
  int f = (idx >> 9) % 80;
  int b = idx / (80 * 512);
  float acc[24];
#pragma unroll
  for (int c = 0; c < 24; ++c) acc[c] = bb[c];
  for (int i = 0; i < 3; ++i) {
    int fi = f - 1 + i;
    bool fok = (fi >= 0 && fi < 80);
    for (int j = 0; j < 3; ++j) {
      int tj = t - 1 + j;
      bool ok = fok && (tj >= 0) && (tj < 512);
      float in_[24];
      if (ok) {
        const float4* src = (const float4*)(p1 + ((size_t)(b * 80 + fi) * 512 + tj) * 24);
#pragma unroll
        for (int q = 0; q < 6; ++q) {
          float4 v = src[q];
          in_[q * 4] = v.x; in_[q * 4 + 1] = v.y; in_[q * 4 + 2] = v.z; in_[q * 4 + 3] = v.w;
        }
      } else {
#pragma unroll
        for (int q = 0; q < 24; ++q) in_[q] = 0.f;
      }
      int ij = i * 3 + j;
#pragma unroll
      for (int ci = 0; ci < 24; ++ci) {
        float iv = in_[ci];
        const float4* wr = (const float4*)&wT[(ci * 9 + ij) * 24];
#pragma unroll
        for (int q = 0; q < 6; ++q) {
          float4 wv = wr[q];
          acc[q * 4 + 0] += wv.x * iv; acc[q * 4 + 1] += wv.y * iv;
          acc[q * 4 + 2] += wv.z * iv; acc[q * 4 + 3] += wv.w * iv;
        }
      }
    }
  }
  float* dst = o2 + (size_t)idx * 24;
#pragma unroll
  for (int q = 0; q < 6; ++q) {
    float4 o;
    o.x = fmaxf(acc[q * 4 + 0], 0.f); o.y = fmaxf(acc[q * 4 + 1], 0.f);
    o.z = fmaxf(acc[q * 4 + 2], 0.f); o.w = fmaxf(acc[q * 4 + 3], 0.f);
    *(float4*)(dst + q * 4) = o;
  }
}

// ---- RB2 conv2 + identity skip + relu + pool + scatter to seq [b,t,960] ----
__global__ __launch_bounds__(256) void k_rb2_rest(const float* __restrict__ o2,
                                                  const float* __restrict__ p1,
                                                  const float* __restrict__ w,
                                                  const float* __restrict__ bias,
                                                  float* __restrict__ seq) {
  __shared__ __align__(16) float wT2[5184];
  __shared__ float bb[24];
  int tid = threadIdx.x;
  for (int l = tid; l < 5184; l += 256) {
    int c = l / 216, r = l % 216;
    wT2[r * 24 + c] = w[l];
  }
  if (tid < 24) bb[tid] = bias[tid];
  __syncthreads();
  int idx = blockIdx.x * 256 + tid;              // (b,f2,t) over 4*40*512
  int t = idx & 511;
  int f2 = (idx >> 9) % 40;
  int b = idx / (40 * 512);
  float acc0[24], acc1[24];
#pragma unroll
  for (int c = 0; c < 24; ++c) { acc0[c] = bb[c]; acc1[c] = bb[c]; }
  for (int fr = 0; fr < 4; ++fr) {
    int fi = 2 * f2 - 1 + fr;
    bool fok = (fi >= 0 && fi < 80);
    for (int jr = 0; jr < 3; ++jr) {
      int tj = t - 1 + jr;
      bool ok = fok && (tj >= 0) && (tj < 512);
      float in_[24];
      if (ok) {
        const float4* src = (const float4*)(o2 + ((size_t)(b * 80 + fi) * 512 + tj) * 24);
#pragma unroll
        for (int q = 0; q < 6; ++q) {
          float4 v = src[q];
          in_[q * 4] = v.x; in_[q * 4 + 1] = v.y; in_[q * 4 + 2] = v.z; in_[q * 4 + 3] = v.w;
        }
      } else {
#pragma unroll
        for (int q = 0; q < 24; ++q) in_[q] = 0.f;
      }
      if (fr < 3) {
        int ij = fr * 3 + jr;
#pragma unroll
        for (int ci = 0; ci < 24; ++ci) {
          float iv = in_[ci];
          const float4* wr = (const float4*)&wT2[(ci * 9 + ij) * 24];
#pragma unroll
          for (int q = 0; q < 6; ++q) {
            float4 wv = wr[q];
            acc0[q * 4 + 0] += wv.x * iv; acc0[q * 4 + 1] += wv.y * iv;
            acc0[q * 4 + 2] += wv.z * iv; acc0[q * 4 + 3] += wv.w * iv;
          }
        }
      }
      if (fr >= 1) {
        int ij = (fr - 1) * 3 + jr;
#pragma unroll
        for (int ci = 0; ci < 24; ++ci) {
          float iv = in_[ci];
          const float4* wr = (const float4*)&wT2[(ci * 9 + ij) * 24];
#pragma unroll
          for (int q = 0; q < 6; ++q) {
            float4 wv = wr[q];
            acc1[q * 4 + 0] += wv.x * iv; acc1[q * 4 + 1] += wv.y * iv;
            acc1[q * 4 + 2] += wv.z * iv; acc1[q * 4 + 3] += wv.w * iv;
          }
        }
      }
    }
  }
  const float* s0p = p1 + ((size_t)(b * 80 + 2 * f2) * 512 + t) * 24;
  const float* s1p = p1 + ((size_t)(b * 80 + 2 * f2 + 1) * 512 + t) * 24;
  float* srow = seq + (size_t)(b * 512 + t) * 960 + f2;
#pragma unroll
  for (int c = 0; c < 24; ++c) {
    float v0 = fmaxf(acc0[c] + s0p[c], 0.f);
    float v1 = fmaxf(acc1[c] + s1p[c], 0.f);
    srow[c * 40] = fmaxf(v0, v1);
  }
}

// ------------- SGEMM C[M,N] = A[M,K] * B[N,K]^T  (both K-contiguous) --------
// 128x128 tile, BK=16, 256 threads, 8x8 micro (split 4+4 rows/cols for
// conflict-free LDS reads covering all 32 banks).
__global__ __launch_bounds__(256) void k_sgemm_nt(const float* __restrict__ A,
                                                  const float* __restrict__ B,
                                                  float* __restrict__ C,
                                                  int M, int N, int K) {
  __shared__ __align__(16) float As[16][132];
  __shared__ __align__(16) float Bs[16][132];
  int tid = threadIdx.x;
  int lr = tid >> 1;            // 0..127 tile row
  int lk = (tid & 1) * 8;       // 0 or 8
  int tm = (tid >> 4) * 4;      // 0..60
  int tn = (tid & 15) * 4;      // 0..60
  int bm = blockIdx.y * 128, bn = blockIdx.x * 128;
  bool bok = (bn + lr) < N;
  const float* Ap = A + (size_t)(bm + lr) * K + lk;
  const float* Bp = B + (size_t)(bok ? (bn + lr) : 0) * K + lk;
  float acc[8][8];
#pragma unroll
  for (int i = 0; i < 8; ++i)
#pragma unroll
    for (int j = 0; j < 8; ++j) acc[i][j] = 0.f;
  float4 z4 = make_float4(0.f, 0.f, 0.f, 0.f);
  float4 a4 = *(const float4*)(Ap);
  float4 a4b = *(const float4*)(Ap + 4);
  float4 b4 = bok ? *(const float4*)(Bp) : z4;
  float4 b4b = bok ? *(const float4*)(Bp + 4) : z4;
  for (int k0 = 0; k0 < K; k0 += 16) {
    __syncthreads();
    As[lk + 0][lr] = a4.x;  As[lk + 1][lr] = a4.y;
    As[lk + 2][lr] = a4.z;  As[lk + 3][lr] = a4.w;
    As[lk + 4][lr] = a4b.x; As[lk + 5][lr] = a4b.y;
    As[lk + 6][lr] = a4b.z; As[lk + 7][lr] = a4b.w;
    Bs[lk + 0][lr] = b4.x;  Bs[lk + 1][lr] = b4.y;
    Bs[lk + 2][lr] = b4.z;  Bs[lk + 3][lr] = b4.w;
    Bs[lk + 4][lr] = b4b.x; Bs[lk + 5][lr] = b4b.y;
    Bs[lk + 6][lr] = b4b.z; Bs[lk + 7][lr] = b4b.w;
    __syncthreads();
    if (k0 + 16 < K) {
      a4  = *(const float4*)(Ap + k0 + 16);
      a4b = *(const float4*)(Ap + k0 + 20);
      b4  = bok ? *(const float4*)(Bp + k0 + 16) : z4;
      b4b = bok ? *(const float4*)(Bp + k0 + 20) : z4;
    }
#pragma unroll
    for (int kk = 0; kk < 16; ++kk) {
      float4 a0 = *(const float4*)&As[kk][tm];
      float4 a1 = *(const float4*)&As[kk][tm + 64];
      float4 b0 = *(const float4*)&Bs[kk][tn];
      float4 b1 = *(const float4*)&Bs[kk][tn + 64];
      float am[8] = {a0.x, a0.y, a0.z, a0.w, a1.x, a1.y, a1.z, a1.w};
      float bv[8] = {b0.x, b0.y, b0.z, b0.w, b1.x, b1.y, b1.z, b1.w};
#pragma unroll
      for (int i = 0; i < 8; ++i)
#pragma unroll
        for (int j = 0; j < 8; ++j) acc[i][j] += am[i] * bv[j];
    }
  }
#pragma unroll
  for (int ih = 0; ih < 2; ++ih) {
#pragma unroll
    for (int i = 0; i < 4; ++i) {
      int row = bm + ih * 64 + tm + i;
#pragma unroll
      for (int jh = 0; jh < 2; ++jh) {
        int col = bn + jh * 64 + tn;
        if (col < N) {
          float4 o = make_float4(acc[ih * 4 + i][jh * 4 + 0], acc[ih * 4 + i][jh * 4 + 1],
                                 acc[ih * 4 + i][jh * 4 + 2], acc[ih * 4 + i][jh * 4 + 3]);
          *(float4*)&C[(size_t)row * N + col] = o;
        }
      }
    }
  }
}

// ------- SGEMM 64(M)x128(N) tile variant: better CU fill for small M*N ------
__global__ __launch_bounds__(256) void k_sgemm_nt64(const float* __restrict__ A,
                                                    const float* __restrict__ B,
                                                    float* __restrict__ C,
                                                    int M, int N, int K) {
  __shared__ __align__(16) float As[16][68];
  __shared__ __align__(16) float Bs[16][132];
  int tid = threadIdx.x;
  int lra = tid >> 2;           // 0..63   A tile row
  int lka = (tid & 3) * 4;      // 0,4,8,12
  int lrb = tid >> 1;           // 0..127  B tile row
  int lkb = (tid & 1) * 8;      // 0 or 8
  int tm = (tid >> 4) * 4;      // 0..60
  int tn = (tid & 15) * 4;      // 0..60
  int bm = blockIdx.y * 64, bn = blockIdx.x * 128;
  bool bok = (bn + lrb) < N;
  const float* Ap = A + (size_t)(bm + lra) * K + lka;
  const float* Bp = B + (size_t)(bok ? (bn + lrb) : 0) * K + lkb;
  float acc[4][8];
#pragma unroll
  for (int i = 0; i < 4; ++i)
#pragma unroll
    for (int j = 0; j < 8; ++j) acc[i][j] = 0.f;
  float4 z4 = make_float4(0.f, 0.f, 0.f, 0.f);
  float4 a4 = *(const float4*)(Ap);
  float4 b4 = bok ? *(const float4*)(Bp) : z4;
  float4 b4b = bok ? *(const float4*)(Bp + 4) : z4;
  for (int k0 = 0; k0 < K; k0 += 16) {
    __syncthreads();
    As[lka + 0][lra] = a4.x; As[lka + 1][lra] = a4.y;
    As[lka + 2][lra] = a4.z; As[lka + 3][lra] = a4.w;
    Bs[lkb + 0][lrb] = b4.x;  Bs[lkb + 1][lrb] = b4.y;
    Bs[lkb + 2][lrb] = b4.z;  Bs[lkb + 3][lrb] = b4.w;
    Bs[lkb + 4][lrb] = b4b.x; Bs[lkb + 5][lrb] = b4b.y;
    Bs[lkb + 6][lrb] = b4b.z; Bs[lkb + 7][lrb] = b4b.w;
    __syncthreads();
    if (k0 + 16 < K) {
      a4  = *(const float4*)(Ap + k0 + 16);
      b4  = bok ? *(const float4*)(Bp + k0 + 16) : z4;
      b4b = bok ? *(const float4*)(Bp + k0 + 20) : z4;
    }
#pragma unroll
    for (int kk = 0; kk < 16; ++kk) {
      float4 a0 = *(const float4*)&As[kk][tm];
      float4 b0 = *(const float4*)&Bs[kk][tn];
      float4 b1 = *(const float4*)&Bs[kk][tn + 64];
      float am[4] = {a0.x, a0.y, a0.z, a0.w};
      float bv[8] = {b0.x, b0.y, b0.z, b0.w, b1.x, b1.y, b1.z, b1.w};
#pragma unroll
      for (int i = 0; i < 4; ++i)
#pragma unroll
        for (int j = 0; j < 8; ++j) acc[i][j] += am[i] * bv[j];
    }
  }
#pragma unroll
  for (int i = 0; i < 4; ++i) {
    int row = bm + tm + i;
#pragma unroll
    for (int jh = 0; jh < 2; ++jh) {
      int col = bn + jh * 64 + tn;
      if (col < N) {
        float4 o = make_float4(acc[i][jh * 4 + 0], acc[i][jh * 4 + 1],
                               acc[i][jh * 4 + 2], acc[i][jh * 4 + 3]);
        *(float4*)&C[(size_t)row * N + col] = o;
      }
    }
  }
}

// ---------------- causal depthwise conv1d + silu ----------------------------
__global__ __launch_bounds__(256) void k_conv1d_silu(const float* __restrict__ xz,
                                                     const float* __restrict__ cw,
                                                     const float* __restrict__ cb,
                                                     float* __restrict__ xc) {
  int idx = blockIdx.x * 256 + threadIdx.x;      // over B*T*DI
  int d = idx % DI;
  int m = idx / DI;
  int t = m & 511;
  int b = m >> 9;
  float4 w4 = *(const float4*)(cw + (size_t)d * 4);
  const float* xin = xz + (size_t)(b * 512) * (2 * DI) + d;
  float s = cb[d];
  if (t >= 3) s += w4.x * xin[(size_t)(t - 3) * (2 * DI)];
  if (t >= 2) s += w4.y * xin[(size_t)(t - 2) * (2 * DI)];
  if (t >= 1) s += w4.z * xin[(size_t)(t - 1) * (2 * DI)];
  s += w4.w * xin[(size_t)t * (2 * DI)];
  xc[idx] = s / (1.f + __expf(-s));
}

// ---------------- x_proj: dbc[2048,92] = xc[2048,1920] * xw[92,1920]^T ------
__global__ __launch_bounds__(256) void k_xproj(const float* __restrict__ xc,
                                               const float* __restrict__ xw,
                                               float* __restrict__ dbc) {
  int idx = blockIdx.x * 256 + threadIdx.x;      // 2048*92 exactly
  int m = idx / 92, j = idx % 92;
  const float4* a = (const float4*)(xc + (size_t)m * DI);
  const float4* w = (const float4*)(xw + (size_t)j * DI);
  float s = 0.f;
#pragma unroll 8
  for (int k = 0; k < DI / 4; ++k) {
    float4 av = a[k], wv = w[k];
    s += av.x * wv.x + av.y * wv.y + av.z * wv.z + av.w * wv.w;
  }
  dbc[(size_t)m * 92 + j] = s;
}

// -------- dt_proj + softplus: dt[2048,1920] ---------------------------------
__global__ __launch_bounds__(256) void k_dtproj(const float* __restrict__ dbc,
                                                const float* __restrict__ dtw,
                                                const float* __restrict__ dtb,
                                                float* __restrict__ dt) {
  int idx = blockIdx.x * 256 + threadIdx.x;      // 2048*1920 exactly
  int m = idx / DI, n = idx % DI;
  const float4* a = (const float4*)(dbc + (size_t)m * 92);   // first 60 floats
  const float4* w = (const float4*)(dtw + (size_t)n * DTR);
  float s = dtb[n];
#pragma unroll
  for (int k = 0; k < DTR / 4; ++k) {
    float4 av = a[k], wv = w[k];
    s += av.x * wv.x + av.y * wv.y + av.z * wv.z + av.w * wv.w;
  }
  float sp = (s > 20.f) ? s : log1pf(__expf(s));
  dt[idx] = sp;
}

// ---------------- selective scan (fused D-residual + z-gate) ----------------
// thread layout: 16 lanes (n) per (b,d); block = 16 (b,d) pairs; grid = 480.
__global__ __launch_bounds__(256) void k_scan(const float* __restrict__ dt,
                                              const float* __restrict__ xc,
                                              const float* __restrict__ dbc,
                                              const float* __restrict__ xz,
                                              const float* __restrict__ A_log,
                                              const float* __restrict__ Dp,
                                              float* __restrict__ y) {
  int tid = threadIdx.x;
  int n = tid & 15, p = tid >> 4;
  int blk = blockIdx.x;
  int b = blk / 120;
  int d = (blk % 120) * 16 + p;
  float a = -__expf(A_log[(size_t)d * NST + n]);
  float dpv = Dp[d];
  float h = 0.f;
  size_t base = (size_t)b * 512;

  float pdt[8], pu[8], pB[8], pC[8], pz[8];
#pragma unroll
  for (int j = 0; j < 8; ++j) {
    size_t m = base + j;
    pdt[j] = dt[m * DI + d];
    pu[j]  = xc[m * DI + d];
    pB[j]  = dbc[m * 92 + 60 + n];
    pC[j]  = dbc[m * 92 + 76 + n];
    pz[j]  = xz[m * (2 * DI) + DI + d];
  }
  for (int t0 = 0; t0 < 512; t0 += 8) {
#pragma unroll
    for (int j = 0; j < 8; ++j) {
      int t = t0 + j;
      float c_dt = pdt[j], c_u = pu[j], c_B = pB[j], c_C = pC[j], c_z = pz[j];
      int tp = t + 8;
      if (tp < 512) {
        size_t m = base + tp;
        pdt[j] = dt[m * DI + d];
        pu[j]  = xc[m * DI + d];
        pB[j]  = dbc[m * 92 + 60 + n];
        pC[j]  = dbc[m * 92 + 76 + n];
        pz[j]  = xz[m * (2 * DI) + DI + d];
      }
      float dA = __expf(c_dt * a);
      h = dA * h + c_dt * c_B * c_u;
      float pv = h * c_C;
      pv += __shfl_xor(pv, 1, 16);
      pv += __shfl_xor(pv, 2, 16);
      pv += __shfl_xor(pv, 4, 16);
      pv += __shfl_xor(pv, 8, 16);
      if (n == 0) {
        float yv = pv + c_u * dpv;
        float sg = c_z / (1.f + __expf(-c_z));
        y[(base + t) * DI + d] = yv * sg;
      }
    }
  }
}

// ---------------- residual add + rmsnorm (in-place on seq) ------------------
__global__ __launch_bounds__(256) void k_addnorm(float* __restrict__ seq,
                                                 const float* __restrict__ res,
                                                 const float* __restrict__ w) {
  int row = blockIdx.x;
  int tid = threadIdx.x;
  __shared__ float red[4];
  float v[4];
  float ss = 0.f;
#pragma unroll
  for (int q = 0; q < 4; ++q) {
    int j = tid + q * 256;
    if (j < 960) {
      float x = res[(size_t)row * 960 + j] + seq[(size_t)row * 960 + j];
      v[q] = x;
      ss += x * x;
    } else v[q] = 0.f;
  }
#pragma unroll
  for (int o = 32; o > 0; o >>= 1) ss += __shfl_xor(ss, o, 64);
  if ((tid & 63) == 0) red[tid >> 6] = ss;
  __syncthreads();
  ss = red[0] + red[1] + red[2] + red[3];
  float rs = rsqrtf(ss / 960.f + 1e-5f);
#pragma unroll
  for (int q = 0; q < 4; ++q) {
    int j = tid + q * 256;
    if (j < 960) seq[(size_t)row * 960 + j] = v[q] * rs * w[j];
  }
}

// ---------------- final fc + relu + transpose to [B,10,T] -------------------
__global__ __launch_bounds__(256) void k_fc(const float* __restrict__ seq,
                                            const float* __restrict__ fw,
                                            const float* __restrict__ fb,
                                            float* __restrict__ out) {
  int idx = blockIdx.x * 256 + threadIdx.x;      // 2048*16
  int m = idx >> 4, c = idx & 15;
  if (c >= 10) return;
  const float4* a = (const float4*)(seq + (size_t)m * 960);
  const float4* w = (const float4*)(fw + (size_t)c * 960);
  float s = fb[c];
#pragma unroll 8
  for (int k = 0; k < 240; ++k) {
    float4 av = a[k], wv = w[k];
    s += av.x * wv.x + av.y * wv.y + av.z * wv.z + av.w * wv.w;
  }
  int b = m >> 9, t = m & 511;
  out[(size_t)(b * 10 + c) * 512 + t] = fmaxf(s, 0.f);
}

// ---------------------------------------------------------------------------
extern "C" void kernel_launch(void* const* d_in, const int* in_sizes, int n_in,
                              void* d_out, int out_size, void* d_ws, size_t ws_size,
                              hipStream_t stream) {
  const float* x       = (const float*)d_in[0];
  const float* cb1_w1  = (const float*)d_in[1];
  const float* cb1_b1  = (const float*)d_in[2];
  const float* cb1_w2  = (const float*)d_in[3];
  const float* cb1_b2  = (const float*)d_in[4];
  const float* cb1_ws  = (const float*)d_in[5];
  const float* cb1_bs  = (const float*)d_in[6];
  const float* cb2_w1  = (const float*)d_in[7];
  const float* cb2_b1  = (const float*)d_in[8];
  const float* cb2_w2  = (const float*)d_in[9];
  const float* cb2_b2  = (const float*)d_in[10];
  const float* in_proj = (const float*)d_in[11];
  const float* c1d_w   = (const float*)d_in[12];
  const float* c1d_b   = (const float*)d_in[13];
  const float* xp_w    = (const float*)d_in[14];
  const float* dtp_w   = (const float*)d_in[15];
  const float* dtp_b   = (const float*)d_in[16];
  const float* A_log   = (const float*)d_in[17];
  const float* D_par   = (const float*)d_in[18];
  const float* op_w    = (const float*)d_in[19];
  const float* nw      = (const float*)d_in[20];
  const float* fc_w    = (const float*)d_in[21];
  const float* fc_b    = (const float*)d_in[22];

  float* W = (float*)d_ws;
  // Region map (floats). CNN phase: h0,o1,p1,o2,seq live.
  // Mamba phase: xz(=o1), xc(=p1), dt(=o2 lo), res(=o2 hi), dbc(=h0), seq, yb.
  float* h0  = W;                     //   327,680
  float* o1  = W + 327680;            // 7,864,320  (reused as xz)
  float* p1  = W + 8192000;           // 3,932,160  (reused as xc)
  float* o2  = W + 12124160;          // 3,932,160  (reused as dt)
  float* seq = W + 16056320;          // 1,966,080
  float* yb  = W + 18022400;          // 3,932,160  -> total 21,954,560 fl (~88MB)
  float* xz  = o1;
  float* xc  = p1;
  float* dtb = o2;
  float* dbc = h0;                    //   188,416  (h0 dead after CNN)
  float* res = o2 + 1966080;          // 1,966,080  (dt hi half unused; dt dead
                                      //             after k_scan anyway)

  // CNN front-end
  k_flux<<<1280, 256, 0, stream>>>(x, h0);
  k_rb1_conv1<<<1280, 256, 0, stream>>>(h0, cb1_w1, cb1_b1, o1);
  k_rb1_rest<<<640, 256, 0, stream>>>(o1, h0, cb1_w2, cb1_b2, cb1_ws, cb1_bs, p1);
  k_rb2_conv1<<<640, 256, 0, stream>>>(p1, cb2_w1, cb2_b1, o2);
  k_rb2_rest<<<320, 256, 0, stream>>>(o2, p1, cb2_w2, cb2_b2, seq);

  // Mamba layers
  for (int i = 0; i < 3; ++i) {
    k_sgemm_nt<<<dim3(30, 16), 256, 0, stream>>>(
        seq, in_proj + (size_t)i * 2 * DI * DM, xz, 2048, 2 * DI, DM);
    k_conv1d_silu<<<15360, 256, 0, stream>>>(
        xz, c1d_w + (size_t)i * DI * 4, c1d_b + (size_t)i * DI, xc);
    k_xproj<<<736, 256, 0, stream>>>(xc, xp_w + (size_t)i * 92 * DI, dbc);
    k_dtproj<<<15360, 256, 0, stream>>>(
        dbc, dtp_w + (size_t)i * DI * DTR, dtp_b + (size_t)i * DI, dtb);
    k_scan<<<480, 256, 0, stream>>>(
        dtb, xc, dbc, xz, A_log + (size_t)i * DI * NST, D_par + (size_t)i * DI, yb);
    k_sgemm_nt64<<<dim3(8, 32), 256, 0, stream>>>(
        yb, op_w + (size_t)i * DM * DI, res, 2048, DM, DI);
    k_addnorm<<<2048, 256, 0, stream>>>(seq, res, nw + (size_t)i * DM);
  }
  k_fc<<<128, 256, 0, stream>>>(seq, fc_w, fc_b, (float*)d_out);
}

// Round 10
// 3310.839 us; speedup vs baseline: 1.1119x; 1.1119x over previous
//
#include <hip/hip_runtime.h>
#include <hip/hip_bf16.h>

// ---------------------------------------------------------------------------
// CNNMambaFast fp32 pipeline for MI355X.
// Shapes: B=4, T=512, mel=80 -> flux 160 -> CNN -> seq [4,512,960]
// 3 Mamba layers (D_INNER=1920, N=16, DT_RANK=60, D_CONV=4) -> fc 10 classes.
// R6: k_scan -> k_scan2 (16x block-parallel chunked scan; occupancy 21%->70%+)
// ---------------------------------------------------------------------------

#define B_ 4
#define T_ 512
#define DM 960
#define DI 1920
#define NST 16
#define DTR 60

// ---------------- flux: [4,80,512] -> h0 [4,160,512] ------------------------
__global__ __launch_bounds__(256) void k_flux(const float* __restrict__ x,
                                              float* __restrict__ h0) {
  int idx = blockIdx.x * 256 + threadIdx.x;      // over 4*160*512
  int t = idx & 511;
  int f = (idx >> 9) % 160;
  int b = idx / (160 * 512);
  float v;
  if (f < 80) {
    v = x[(size_t)(b * 80 + f) * 512 + t];
  } else {
    int fm = f - 80;
    v = (t == 0) ? 0.f
                 : fmaxf(x[(size_t)(b * 80 + fm) * 512 + t] -
                         x[(size_t)(b * 80 + fm) * 512 + t - 1], 0.f);
  }
  h0[idx] = v;
}

// ---------------- RB1 conv1 (1->24, 3x3, relu), channels-last out -----------
__global__ __launch_bounds__(256) void k_rb1_conv1(const float* __restrict__ h0,
                                                   const float* __restrict__ w1,
                                                   const float* __restrict__ b1,
                                                   float* __restrict__ o1) {
  __shared__ __align__(16) float wT[9][24];
  __shared__ float bb[24];
  int tid = threadIdx.x;
  if (tid < 216) wT[tid % 9][tid / 9] = w1[tid];
  if (tid >= 216 && tid < 240) bb[tid - 216] = b1[tid - 216];
  __syncthreads();
  int idx = blockIdx.x * 256 + tid;              // (b,f,t) over 4*160*512
  int t = idx & 511;
  int f = (idx >> 9) % 160;
  int b = idx / (160 * 512);
  float acc[24];
#pragma unroll
  for (int c = 0; c < 24; ++c) acc[c] = bb[c];
#pragma unroll
  for (int i = 0; i < 3; ++i) {
    int fi = f - 1 + i;
    if (fi < 0 || fi >= 160) continue;
#pragma unroll
    for (int j = 0; j < 3; ++j) {
      int tj = t - 1 + j;
      if (tj < 0 || tj >= 512) continue;
      float v = h0[((size_t)(b * 160 + fi) << 9) + tj];
      const float4* wr = (const float4*)&wT[i * 3 + j][0];
#pragma unroll
      for (int q = 0; q < 6; ++q) {
        float4 wv = wr[q];
        acc[q * 4 + 0] += wv.x * v; acc[q * 4 + 1] += wv.y * v;
        acc[q * 4 + 2] += wv.z * v; acc[q * 4 + 3] += wv.w * v;
      }
    }
  }
  float* dst = o1 + (size_t)idx * 24;
#pragma unroll
  for (int q = 0; q < 6; ++q) {
    float4 o;
    o.x = fmaxf(acc[q * 4 + 0], 0.f); o.y = fmaxf(acc[q * 4 + 1], 0.f);
    o.z = fmaxf(acc[q * 4 + 2], 0.f); o.w = fmaxf(acc[q * 4 + 3], 0.f);
    *(float4*)(dst + q * 4) = o;
  }
}

// ------------- RB1 conv2 + 1x1 skip + relu + maxpool(2,1) -------------------
__global__ __launch_bounds__(256) void k_rb1_rest(const float* __restrict__ o1,
                                                  const float* __restrict__ h0,
                                                  const float* __restrict__ w2,
                                                  const float* __restrict__ b2,
                                                  const float* __restrict__ wsk,
                                                  const float* __restrict__ bsk,
                                                  float* __restrict__ p1) {
  __shared__ __align__(16) float wT2[5184];   // [ci][ij][c]
  __shared__ float bb[24], wss[24], bss[24];
  int tid = threadIdx.x;
  for (int l = tid; l < 5184; l += 256) {
    int c = l / 216, r = l % 216;
    wT2[r * 24 + c] = w2[l];
  }
  if (tid < 24) { bb[tid] = b2[tid]; wss[tid] = wsk[tid]; bss[tid] = bsk[tid]; }
  __syncthreads();
  int idx = blockIdx.x * 256 + tid;              // (b,f2,t) over 4*80*512
  int t = idx & 511;
  int f2 = (idx >> 9) % 80;
  int b = idx / (80 * 512);
  float acc0[24], acc1[24];
#pragma unroll
  for (int c = 0; c < 24; ++c) { acc0[c] = bb[c]; acc1[c] = bb[c]; }
  for (int fr = 0; fr < 4; ++fr) {
    int fi = 2 * f2 - 1 + fr;
    bool fok = (fi >= 0 && fi < 160);
    for (int jr = 0; jr < 3; ++jr) {
      int tj = t - 1 + jr;
      bool ok = fok && (tj >= 0) && (tj < 512);
      float in_[24];
      if (ok) {
        const float4* src = (const float4*)(o1 + ((size_t)(b * 160 + fi) * 512 + tj) * 24);
#pragma unroll
        for (int q = 0; q < 6; ++q) {
          float4 v = src[q];
          in_[q * 4] = v.x; in_[q * 4 + 1] = v.y; in_[q * 4 + 2] = v.z; in_[q * 4 + 3] = v.w;
        }
      } else {
#pragma unroll
        for (int q = 0; q < 24; ++q) in_[q] = 0.f;
      }
      if (fr < 3) {
        int ij = fr * 3 + jr;
#pragma unroll
        for (int ci = 0; ci < 24; ++ci) {
          float iv = in_[ci];
          const float4* wr = (const float4*)&wT2[(ci * 9 + ij) * 24];
#pragma unroll
          for (int q = 0; q < 6; ++q) {
            float4 wv = wr[q];
            acc0[q * 4 + 0] += wv.x * iv; acc0[q * 4 + 1] += wv.y * iv;
            acc0[q * 4 + 2] += wv.z * iv; acc0[q * 4 + 3] += wv.w * iv;
          }
        }
      }
      if (fr >= 1) {
        int ij = (fr - 1) * 3 + jr;
#pragma unroll
        for (int ci = 0; ci < 24; ++ci) {
          float iv = in_[ci];
          const float4* wr = (const float4*)&wT2[(ci * 9 + ij) * 24];
#pragma unroll
          for (int q = 0; q < 6; ++q) {
            float4 wv = wr[q];
            acc1[q * 4 + 0] += wv.x * iv; acc1[q * 4 + 1] += wv.y * iv;
            acc1[q * 4 + 2] += wv.z * iv; acc1[q * 4 + 3] += wv.w * iv;
          }
        }
      }
    }
  }
  float h0a = h0[((size_t)(b * 160 + 2 * f2) << 9) + t];
  float h0b = h0[((size_t)(b * 160 + 2 * f2 + 1) << 9) + t];
  float* dst = p1 + (size_t)idx * 24;
#pragma unroll
  for (int q = 0; q < 6; ++q) {
    float4 o;
#pragma unroll
    for (int e = 0; e < 4; ++e) {
      int c = q * 4 + e;
      float v0 = fmaxf(acc0[c] + wss[c] * h0a + bss[c], 0.f);
      float v1 = fmaxf(acc1[c] + wss[c] * h0b + bss[c], 0.f);
      ((float*)&o)[e] = fmaxf(v0, v1);
    }
    *(float4*)(dst + q * 4) = o;
  }
}

// ---------------- RB2 conv1 (24->24, 3x3, relu) -----------------------------
__global__ __launch_bounds__(256) void k_rb2_conv1(const float* __restrict__ p1,
                                                   const float* __restrict__ w,
                                                   const float* __restrict__ bias,
                                                   float* __restrict__ o2) {
  __shared__ __align__(16) float wT[5184];
  __shared__ float bb[24];
  int tid = threadIdx.x;
  for (int l = tid; l < 5184; l += 256) {
    int c = l / 216, r = l % 216;
    wT[r * 24 + c] = w[l];
  }
  if (tid < 24) bb[tid] = bias[tid];
  __syncthreads();
  int idx = blockIdx.x * 256 + tid;              // (b,f,t) over 4*80*512
  int t = idx & 511;
  int f = (idx >> 9) % 80;
  int b = idx / (80 * 512);
  float acc[24];
#pragma unroll
  for (int c = 0; c < 24; ++c) acc[c] = bb[c];
  for (int i = 0; i < 3; ++i) {
    int fi = f - 1 + i;
    bool fok = (fi >= 0 && fi < 80);
    for (int j = 0; j < 3; ++j) {
      int tj = t - 1 + j;
      bool ok = fok && (tj >= 0) && (tj < 512);
      float in_[24];
      if (ok) {
        const float4* src = (const float4*)(p1 + ((size_t)(b * 80 + fi) * 512 + tj) * 24);
#pragma unroll
        for (int q = 0; q < 6; ++q) {
          float4 v = src[q];
          in_[q * 4] = v.x; in_[q * 4 + 1] = v.y; in_[q * 4 + 2] = v.z; in_[q * 4 + 3] = v.w;
        }
      } else {
#pragma unroll
        for (int q = 0; q < 24; ++q) in_[q] = 0.f;
      }
      int ij = i * 3 + j;
#pragma unroll
      for (int ci = 0; ci < 24; ++ci) {
        float iv = in_[ci];
        const float4* wr = (const float4*)&wT[(ci * 9 + ij) * 24];
#pragma unroll
        for (int q = 0; q < 6; ++q) {
          float4 wv = wr[q];
          acc[q * 4 + 0] += wv.x * iv; acc[q * 4 + 1] += wv.y * iv;
          acc[q * 4 + 2] += wv.z * iv; acc[q * 4 + 3] += wv.w * iv;
        }
      }
    }
  }
  float* dst = o2 + (size_t)idx * 24;
#pragma unroll
  for (int q = 0; q < 6; ++q) {
    float4 o;
    o.x = fmaxf(acc[q * 4 + 0], 0.f); o.y = fmaxf(acc[q * 4 + 1], 0.f);
    o.z = fmaxf(acc[q * 4 + 2], 0.f); o.w = fmaxf(acc[q * 4 + 3], 0.f);
    *(float4*)(dst + q * 4) = o;
  }
}

// ---- RB2 conv2 + identity skip + relu + pool + scatter to seq [b,t,960] ----
__global__ __launch_bounds__(256) void k_rb2_rest(const float* __restrict__ o2,
                                                  const float* __restrict__ p1,
                                                  const float* __restrict__ w,
                                                  const float* __restrict__ bias,
                                                  float* __restrict__ seq) {
  __shared__ __align__(16) float wT2[5184];
  __shared__ float bb[24];
  int tid = threadIdx.x;
  for (int l = tid; l < 5184; l += 256) {
    int c = l / 216, r = l % 216;
    wT2[r * 24 + c] = w[l];
  }
  if (tid < 24) bb[tid] = bias[tid];
  __syncthreads();
  int idx = blockIdx.x * 256 + tid;              // (b,f2,t) over 4*40*512
  int t = idx & 511;
  int f2 = (idx >> 9) % 40;
  int b = idx / (40 * 512);
  float acc0[24], acc1[24];
#pragma unroll
  for (int c = 0; c < 24; ++c) { acc0[c] = bb[c]; acc1[c] = bb[c]; }
  for (int fr = 0; fr < 4; ++fr) {
    int fi = 2 * f2 - 1 + fr;
    bool fok = (fi >= 0 && fi < 80);
    for (int jr = 0; jr < 3; ++jr) {
      int tj = t - 1 + jr;
      bool ok = fok && (tj >= 0) && (tj < 512);
      float in_[24];
      if (ok) {
        const float4* src = (const float4*)(o2 + ((size_t)(b * 80 + fi) * 512 + tj) * 24);
#pragma unroll
        for (int q = 0; q < 6; ++q) {
          float4 v = src[q];
          in_[q * 4] = v.x; in_[q * 4 + 1] = v.y; in_[q * 4 + 2] = v.z; in_[q * 4 + 3] = v.w;
        }
      } else {
#pragma unroll
        for (int q = 0; q < 24; ++q) in_[q] = 0.f;
      }
      if (fr < 3) {
        int ij = fr * 3 + jr;
#pragma unroll
        for (int ci = 0; ci < 24; ++ci) {
          float iv = in_[ci];
          const float4* wr = (const float4*)&wT2[(ci * 9 + ij) * 24];
#pragma unroll
          for (int q = 0; q < 6; ++q) {
            float4 wv = wr[q];
            acc0[q * 4 + 0] += wv.x * iv; acc0[q * 4 + 1] += wv.y * iv;
            acc0[q * 4 + 2] += wv.z * iv; acc0[q * 4 + 3] += wv.w * iv;
          }
        }
      }
      if (fr >= 1) {
        int ij = (fr - 1) * 3 + jr;
#pragma unroll
        for (int ci = 0; ci < 24; ++ci) {
          float iv = in_[ci];
          const float4* wr = (const float4*)&wT2[(ci * 9 + ij) * 24];
#pragma unroll
          for (int q = 0; q < 6; ++q) {
            float4 wv = wr[q];
            acc1[q * 4 + 0] += wv.x * iv; acc1[q * 4 + 1] += wv.y * iv;
            acc1[q * 4 + 2] += wv.z * iv; acc1[q * 4 + 3] += wv.w * iv;
          }
        }
      }
    }
  }
  const float* s0p = p1 + ((size_t)(b * 80 + 2 * f2) * 512 + t) * 24;
  const float* s1p = p1 + ((size_t)(b * 80 + 2 * f2 + 1) * 512 + t) * 24;
  float* srow = seq + (size_t)(b * 512 + t) * 960 + f2;
#pragma unroll
  for (int c = 0; c < 24; ++c) {
    float v0 = fmaxf(acc0[c] + s0p[c], 0.f);
    float v1 = fmaxf(acc1[c] + s1p[c], 0.f);
    srow[c * 40] = fmaxf(v0, v1);
  }
}

// ------------- SGEMM C[M,N] = A[M,K] * B[N,K]^T  (both K-contiguous) --------
__global__ __launch_bounds__(256) void k_sgemm_nt(const float* __restrict__ A,
                                                  const float* __restrict__ B,
                                                  float* __restrict__ C,
                                                  int M, int N, int K) {
  __shared__ __align__(16) float As[16][132];
  __shared__ __align__(16) float Bs[16][132];
  int tid = threadIdx.x;
  int lr = tid >> 1;            // 0..127 tile row
  int lk = (tid & 1) * 8;       // 0 or 8
  int tm = (tid >> 4) * 4;      // 0..60
  int tn = (tid & 15) * 4;      // 0..60
  int bm = blockIdx.y * 128, bn = blockIdx.x * 128;
  bool bok = (bn + lr) < N;
  const float* Ap = A + (size_t)(bm + lr) * K + lk;
  const float* Bp = B + (size_t)(bok ? (bn + lr) : 0) * K + lk;
  float acc[8][8];
#pragma unroll
  for (int i = 0; i < 8; ++i)
#pragma unroll
    for (int j = 0; j < 8; ++j) acc[i][j] = 0.f;
  float4 z4 = make_float4(0.f, 0.f, 0.f, 0.f);
  float4 a4 = *(const float4*)(Ap);
  float4 a4b = *(const float4*)(Ap + 4);
  float4 b4 = bok ? *(const float4*)(Bp) : z4;
  float4 b4b = bok ? *(const float4*)(Bp + 4) : z4;
  for (int k0 = 0; k0 < K; k0 += 16) {
    __syncthreads();
    As[lk + 0][lr] = a4.x;  As[lk + 1][lr] = a4.y;
    As[lk + 2][lr] = a4.z;  As[lk + 3][lr] = a4.w;
    As[lk + 4][lr] = a4b.x; As[lk + 5][lr] = a4b.y;
    As[lk + 6][lr] = a4b.z; As[lk + 7][lr] = a4b.w;
    Bs[lk + 0][lr] = b4.x;  Bs[lk + 1][lr] = b4.y;
    Bs[lk + 2][lr] = b4.z;  Bs[lk + 3][lr] = b4.w;
    Bs[lk + 4][lr] = b4b.x; Bs[lk + 5][lr] = b4b.y;
    Bs[lk + 6][lr] = b4b.z; Bs[lk + 7][lr] = b4b.w;
    __syncthreads();
    if (k0 + 16 < K) {
      a4  = *(const float4*)(Ap + k0 + 16);
      a4b = *(const float4*)(Ap + k0 + 20);
      b4  = bok ? *(const float4*)(Bp + k0 + 16) : z4;
      b4b = bok ? *(const float4*)(Bp + k0 + 20) : z4;
    }
#pragma unroll
    for (int kk = 0; kk < 16; ++kk) {
      float4 a0 = *(const float4*)&As[kk][tm];
      float4 a1 = *(const float4*)&As[kk][tm + 64];
      float4 b0 = *(const float4*)&Bs[kk][tn];
      float4 b1 = *(const float4*)&Bs[kk][tn + 64];
      float am[8] = {a0.x, a0.y, a0.z, a0.w, a1.x, a1.y, a1.z, a1.w};
      float bv[8] = {b0.x, b0.y, b0.z, b0.w, b1.x, b1.y, b1.z, b1.w};
#pragma unroll
      for (int i = 0; i < 8; ++i)
#pragma unroll
        for (int j = 0; j < 8; ++j) acc[i][j] += am[i] * bv[j];
    }
  }
#pragma unroll
  for (int ih = 0; ih < 2; ++ih) {
#pragma unroll
    for (int i = 0; i < 4; ++i) {
      int row = bm + ih * 64 + tm + i;
#pragma unroll
      for (int jh = 0; jh < 2; ++jh) {
        int col = bn + jh * 64 + tn;
        if (col < N) {
          float4 o = make_float4(acc[ih * 4 + i][jh * 4 + 0], acc[ih * 4 + i][jh * 4 + 1],
                                 acc[ih * 4 + i][jh * 4 + 2], acc[ih * 4 + i][jh * 4 + 3]);
          *(float4*)&C[(size_t)row * N + col] = o;
        }
      }
    }
  }
}

// ------- SGEMM 64(M)x128(N) tile variant: better CU fill for small M*N ------
__global__ __launch_bounds__(256) void k_sgemm_nt64(const float* __restrict__ A,
                                                    const float* __restrict__ B,
                                                    float* __restrict__ C,
                                                    int M, int N, int K) {
  __shared__ __align__(16) float As[16][68];
  __shared__ __align__(16) float Bs[16][132];
  int tid = threadIdx.x;
  int lra = tid >> 2;           // 0..63   A tile row
  int lka = (tid & 3) * 4;      // 0,4,8,12
  int lrb = tid >> 1;           // 0..127  B tile row
  int lkb = (tid & 1) * 8;      // 0 or 8
  int tm = (tid >> 4) * 4;      // 0..60
  int tn = (tid & 15) * 4;      // 0..60
  int bm = blockIdx.y * 64, bn = blockIdx.x * 128;
  bool bok = (bn + lrb) < N;
  const float* Ap = A + (size_t)(bm + lra) * K + lka;
  const float* Bp = B + (size_t)(bok ? (bn + lrb) : 0) * K + lkb;
  float acc[4][8];
#pragma unroll
  for (int i = 0; i < 4; ++i)
#pragma unroll
    for (int j = 0; j < 8; ++j) acc[i][j] = 0.f;
  float4 z4 = make_float4(0.f, 0.f, 0.f, 0.f);
  float4 a4 = *(const float4*)(Ap);
  float4 b4 = bok ? *(const float4*)(Bp) : z4;
  float4 b4b = bok ? *(const float4*)(Bp + 4) : z4;
  for (int k0 = 0; k0 < K; k0 += 16) {
    __syncthreads();
    As[lka + 0][lra] = a4.x; As[lka + 1][lra] = a4.y;
    As[lka + 2][lra] = a4.z; As[lka + 3][lra] = a4.w;
    Bs[lkb + 0][lrb] = b4.x;  Bs[lkb + 1][lrb] = b4.y;
    Bs[lkb + 2][lrb] = b4.z;  Bs[lkb + 3][lrb] = b4.w;
    Bs[lkb + 4][lrb] = b4b.x; Bs[lkb + 5][lrb] = b4b.y;
    Bs[lkb + 6][lrb] = b4b.z; Bs[lkb + 7][lrb] = b4b.w;
    __syncthreads();
    if (k0 + 16 < K) {
      a4  = *(const float4*)(Ap + k0 + 16);
      b4  = bok ? *(const float4*)(Bp + k0 + 16) : z4;
      b4b = bok ? *(const float4*)(Bp + k0 + 20) : z4;
    }
#pragma unroll
    for (int kk = 0; kk < 16; ++kk) {
      float4 a0 = *(const float4*)&As[kk][tm];
      float4 b0 = *(const float4*)&Bs[kk][tn];
      float4 b1 = *(const float4*)&Bs[kk][tn + 64];
      float am[4] = {a0.x, a0.y, a0.z, a0.w};
      float bv[8] = {b0.x, b0.y, b0.z, b0.w, b1.x, b1.y, b1.z, b1.w};
#pragma unroll
      for (int i = 0; i < 4; ++i)
#pragma unroll
        for (int j = 0; j < 8; ++j) acc[i][j] += am[i] * bv[j];
    }
  }
#pragma unroll
  for (int i = 0; i < 4; ++i) {
    int row = bm + tm + i;
#pragma unroll
    for (int jh = 0; jh < 2; ++jh) {
      int col = bn + jh * 64 + tn;
      if (col < N) {
        float4 o = make_float4(acc[i][jh * 4 + 0], acc[i][jh * 4 + 1],
                               acc[i][jh * 4 + 2], acc[i][jh * 4 + 3]);
        *(float4*)&C[(size_t)row * N + col] = o;
      }
    }
  }
}

// ---------------- causal depthwise conv1d + silu ----------------------------
__global__ __launch_bounds__(256) void k_conv1d_silu(const float* __restrict__ xz,
                                                     const float* __restrict__ cw,
                                                     const float* __restrict__ cb,
                                                     float* __restrict__ xc) {
  int idx = blockIdx.x * 256 + threadIdx.x;      // over B*T*DI
  int d = idx % DI;
  int m = idx / DI;
  int t = m & 511;
  int b = m >> 9;
  float4 w4 = *(const float4*)(cw + (size_t)d * 4);
  const float* xin = xz + (size_t)(b * 512) * (2 * DI) + d;
  float s = cb[d];
  if (t >= 3) s += w4.x * xin[(size_t)(t - 3) * (2 * DI)];
  if (t >= 2) s += w4.y * xin[(size_t)(t - 2) * (2 * DI)];
  if (t >= 1) s += w4.z * xin[(size_t)(t - 1) * (2 * DI)];
  s += w4.w * xin[(size_t)t * (2 * DI)];
  xc[idx] = s / (1.f + __expf(-s));
}

// ---------------- x_proj: dbc[2048,92] = xc[2048,1920] * xw[92,1920]^T ------
__global__ __launch_bounds__(256) void k_xproj(const float* __restrict__ xc,
                                               const float* __restrict__ xw,
                                               float* __restrict__ dbc) {
  int idx = blockIdx.x * 256 + threadIdx.x;      // 2048*92 exactly
  int m = idx / 92, j = idx % 92;
  const float4* a = (const float4*)(xc + (size_t)m * DI);
  const float4* w = (const float4*)(xw + (size_t)j * DI);
  float s = 0.f;
#pragma unroll 8
  for (int k = 0; k < DI / 4; ++k) {
    float4 av = a[k], wv = w[k];
    s += av.x * wv.x + av.y * wv.y + av.z * wv.z + av.w * wv.w;
  }
  dbc[(size_t)m * 92 + j] = s;
}

// -------- dt_proj + softplus: dt[2048,1920] ---------------------------------
__global__ __launch_bounds__(256) void k_dtproj(const float* __restrict__ dbc,
                                                const float* __restrict__ dtw,
                                                const float* __restrict__ dtb,
                                                float* __restrict__ dt) {
  int idx = blockIdx.x * 256 + threadIdx.x;      // 2048*1920 exactly
  int m = idx / DI, n = idx % DI;
  const float4* a = (const float4*)(dbc + (size_t)m * 92);   // first 60 floats
  const float4* w = (const float4*)(dtw + (size_t)n * DTR);
  float s = dtb[n];
#pragma unroll
  for (int k = 0; k < DTR / 4; ++k) {
    float4 av = a[k], wv = w[k];
    s += av.x * wv.x + av.y * wv.y + av.z * wv.z + av.w * wv.w;
  }
  float sp = (s > 20.f) ? s : log1pf(__expf(s));
  dt[idx] = sp;
}

// ------ selective scan v2: block-parallel chunked scan over time ------------
// One block per (b,d): 16 segment-groups x 16 n-lanes. Each segment scans 32
// steps from h=0 (phase 1), block-combine fixes segment inits via
// E_s = H_s + P_s*E_{s-1} (decay P = exp(a*sum dt), contractive), phase 2
// rescans with correct init and emits y with D-residual + z-gate fused.
__global__ __launch_bounds__(256) void k_scan2(const float* __restrict__ dt,
                                               const float* __restrict__ xc,
                                               const float* __restrict__ dbc,
                                               const float* __restrict__ xz,
                                               const float* __restrict__ A_log,
                                               const float* __restrict__ Dp,
                                               float* __restrict__ y) {
  int tid = threadIdx.x;
  int n = tid & 15, sg = tid >> 4;               // lane-in-group, segment
  int blk = blockIdx.x;                          // 4*1920 = 7680
  int b = blk / DI;
  int d = blk % DI;
  float a = -__expf(A_log[(size_t)d * NST + n]);
  float dpv = Dp[d];
  size_t base = (size_t)b * 512 + sg * 32;       // first time-row of segment

  __shared__ float sH[16][16];                   // segment end-state
  __shared__ float sP[16][16];                   // segment decay product
  __shared__ float sI[16][16];                   // segment init state

  // ---- phase 1: local scan from h=0; accumulate sum(dt) for decay ----
  float h = 0.f, sdt = 0.f;
#pragma unroll 4
  for (int j = 0; j < 32; ++j) {
    size_t m = base + j;
    float c_dt = dt[m * DI + d];
    float c_u  = xc[m * DI + d];
    float c_B  = dbc[m * 92 + 60 + n];
    float dA = __expf(c_dt * a);
    h = dA * h + c_dt * c_B * c_u;
    sdt += c_dt;
  }
  sH[sg][n] = h;
  sP[sg][n] = __expf(sdt * a);
  __syncthreads();

  // ---- combine: 16 sequential segment steps, done by group 0 ----
  if (sg == 0) {
    float E = 0.f;
#pragma unroll
    for (int s = 0; s < 16; ++s) {
      sI[s][n] = E;
      E = sH[s][n] + sP[s][n] * E;
    }
  }
  __syncthreads();

  // ---- phase 2: rescan from correct init; emit gated output ----
  h = sI[sg][n];
#pragma unroll 4
  for (int j = 0; j < 32; ++j) {
    size_t m = base + j;
    float c_dt = dt[m * DI + d];
    float c_u  = xc[m * DI + d];
    float c_B  = dbc[m * 92 + 60 + n];
    float c_C  = dbc[m * 92 + 76 + n];
    float dA = __expf(c_dt * a);
    h = dA * h + c_dt * c_B * c_u;
    float pv = h * c_C;
    pv += __shfl_xor(pv, 1, 16);
    pv += __shfl_xor(pv, 2, 16);
    pv += __shfl_xor(pv, 4, 16);
    pv += __shfl_xor(pv, 8, 16);
    if (n == 0) {
      float c_z = xz[m * (2 * DI) + DI + d];
      float sgate = c_z / (1.f + __expf(-c_z));
      y[m * DI + d] = (pv + c_u * dpv) * sgate;
    }
  }
}

// ---------------- residual add + rmsnorm (in-place on seq) ------------------
__global__ __launch_bounds__(256) void k_addnorm(float* __restrict__ seq,
                                                 const float* __restrict__ res,
                                                 const float* __restrict__ w) {
  int row = blockIdx.x;
  int tid = threadIdx.x;
  __shared__ float red[4];
  float v[4];
  float ss = 0.f;
#pragma unroll
  for (int q = 0; q < 4; ++q) {
    int j = tid + q * 256;
    if (j < 960) {
      float x = res[(size_t)row * 960 + j] + seq[(size_t)row * 960 + j];
      v[q] = x;
      ss += x * x;
    } else v[q] = 0.f;
  }
#pragma unroll
  for (int o = 32; o > 0; o >>= 1) ss += __shfl_xor(ss, o, 64);
  if ((tid & 63) == 0) red[tid >> 6] = ss;
  __syncthreads();
  ss = red[0] + red[1] + red[2] + red[3];
  float rs = rsqrtf(ss / 960.f + 1e-5f);
#pragma unroll
  for (int q = 0; q < 4; ++q) {
    int j = tid + q * 256;
    if (j < 960) seq[(size_t)row * 960 + j] = v[q] * rs * w[j];
  }
}

// ---------------- final fc + relu + transpose to [B,10,T] -------------------
__global__ __launch_bounds__(256) void k_fc(const float* __restrict__ seq,
                                            const float* __restrict__ fw,
                                            const float* __restrict__ fb,
                                            float* __restrict__ out) {
  int idx = blockIdx.x * 256 + threadIdx.x;      // 2048*16
  int m = idx >> 4, c = idx & 15;
  if (c >= 10) return;
  const float4* a = (const float4*)(seq + (size_t)m * 960);
  const float4* w = (const float4*)(fw + (size_t)c * 960);
  float s = fb[c];
#pragma unroll 8
  for (int k = 0; k < 240; ++k) {
    float4 av = a[k], wv = w[k];
    s += av.x * wv.x + av.y * wv.y + av.z * wv.z + av.w * wv.w;
  }
  int b = m >> 9, t = m & 511;
  out[(size_t)(b * 10 + c) * 512 + t] = fmaxf(s, 0.f);
}

// ---------------------------------------------------------------------------
extern "C" void kernel_launch(void* const* d_in, const int* in_sizes, int n_in,
                              void* d_out, int out_size, void* d_ws, size_t ws_size,
                              hipStream_t stream) {
  const float* x       = (const float*)d_in[0];
  const float* cb1_w1  = (const float*)d_in[1];
  const float* cb1_b1  = (const float*)d_in[2];
  const float* cb1_w2  = (const float*)d_in[3];
  const float* cb1_b2  = (const float*)d_in[4];
  const float* cb1_ws  = (const float*)d_in[5];
  const float* cb1_bs  = (const float*)d_in[6];
  const float* cb2_w1  = (const float*)d_in[7];
  const float* cb2_b1  = (const float*)d_in[8];
  const float* cb2_w2  = (const float*)d_in[9];
  const float* cb2_b2  = (const float*)d_in[10];
  const float* in_proj = (const float*)d_in[11];
  const float* c1d_w   = (const float*)d_in[12];
  const float* c1d_b   = (const float*)d_in[13];
  const float* xp_w    = (const float*)d_in[14];
  const float* dtp_w   = (const float*)d_in[15];
  const float* dtp_b   = (const float*)d_in[16];
  const float* A_log   = (const float*)d_in[17];
  const float* D_par   = (const float*)d_in[18];
  const float* op_w    = (const float*)d_in[19];
  const float* nw      = (const float*)d_in[20];
  const float* fc_w    = (const float*)d_in[21];
  const float* fc_b    = (const float*)d_in[22];

  float* W = (float*)d_ws;
  // Region map (floats). CNN phase: h0,o1,p1,o2,seq live.
  // Mamba phase: xz(=o1), xc(=p1), dt(=o2 lo), res(=o2 hi), dbc(=h0), seq, yb.
  float* h0  = W;                     //   327,680
  float* o1  = W + 327680;            // 7,864,320  (reused as xz)
  float* p1  = W + 8192000;           // 3,932,160  (reused as xc)
  float* o2  = W + 12124160;          // 3,932,160  (reused as dt)
  float* seq = W + 16056320;          // 1,966,080
  float* yb  = W + 18022400;          // 3,932,160  -> total 21,954,560 fl (~88MB)
  float* xz  = o1;
  float* xc  = p1;
  float* dtb = o2;
  float* dbc = h0;                    //   188,416  (h0 dead after CNN)
  float* res = o2 + 1966080;          // 1,966,080  (dt hi half unused; dt dead
                                      //             after k_scan2 anyway)

  // CNN front-end
  k_flux<<<1280, 256, 0, stream>>>(x, h0);
  k_rb1_conv1<<<1280, 256, 0, stream>>>(h0, cb1_w1, cb1_b1, o1);
  k_rb1_rest<<<640, 256, 0, stream>>>(o1, h0, cb1_w2, cb1_b2, cb1_ws, cb1_bs, p1);
  k_rb2_conv1<<<640, 256, 0, stream>>>(p1, cb2_w1, cb2_b1, o2);
  k_rb2_rest<<<320, 256, 0, stream>>>(o2, p1, cb2_w2, cb2_b2, seq);

  // Mamba layers
  for (int i = 0; i < 3; ++i) {
    k_sgemm_nt<<<dim3(30, 16), 256, 0, stream>>>(
        seq, in_proj + (size_t)i * 2 * DI * DM, xz, 2048, 2 * DI, DM);
    k_conv1d_silu<<<15360, 256, 0, stream>>>(
        xz, c1d_w + (size_t)i * DI * 4, c1d_b + (size_t)i * DI, xc);
    k_xproj<<<736, 256, 0, stream>>>(xc, xp_w + (size_t)i * 92 * DI, dbc);
    k_dtproj<<<15360, 256, 0, stream>>>(
        dbc, dtp_w + (size_t)i * DI * DTR, dtp_b + (size_t)i * DI, dtb);
    k_scan2<<<7680, 256, 0, stream>>>(
        dtb, xc, dbc, xz, A_log + (size_t)i * DI * NST, D_par + (size_t)i * DI, yb);
    k_sgemm_nt64<<<dim3(8, 32), 256, 0, stream>>>(
        yb, op_w + (size_t)i * DM * DI, res, 2048, DM, DI);
    k_addnorm<<<2048, 256, 0, stream>>>(seq, res, nw + (size_t)i * DM);
  }
  k_fc<<<128, 256, 0, stream>>>(seq, fc_w, fc_b, (float*)d_out);
}

// Round 14
// 2350.339 us; speedup vs baseline: 1.5662x; 1.4087x over previous
//
#include <hip/hip_runtime.h>
#include <hip/hip_bf16.h>

// ---------------------------------------------------------------------------
// CNNMambaFast fp32 pipeline for MI355X.
// R6:  k_scan2 chunked scan (validated: scan 320 -> <40 us/layer)
// R10: grid-starved GEMMs -> 64x128 dbuf tiles + split-K out_proj;
//      xproj/dtproj lane-strided weight reads -> coalesced rewrites.
// ---------------------------------------------------------------------------

#define B_ 4
#define T_ 512
#define DM 960
#define DI 1920
#define NST 16
#define DTR 60
#define PSTRIDE 1966080   // floats per out_proj partial (2048*960)

// ---------------- flux: [4,80,512] -> h0 [4,160,512] ------------------------
__global__ __launch_bounds__(256) void k_flux(const float* __restrict__ x,
                                              float* __restrict__ h0) {
  int idx = blockIdx.x * 256 + threadIdx.x;
  int t = idx & 511;
  int f = (idx >> 9) % 160;
  int b = idx / (160 * 512);
  float v;
  if (f < 80) {
    v = x[(size_t)(b * 80 + f) * 512 + t];
  } else {
    int fm = f - 80;
    v = (t == 0) ? 0.f
                 : fmaxf(x[(size_t)(b * 80 + fm) * 512 + t] -
                         x[(size_t)(b * 80 + fm) * 512 + t - 1], 0.f);
  }
  h0[idx] = v;
}

// ---------------- RB1 conv1 (1->24, 3x3, relu), channels-last out -----------
__global__ __launch_bounds__(256) void k_rb1_conv1(const float* __restrict__ h0,
                                                   const float* __restrict__ w1,
                                                   const float* __restrict__ b1,
                                                   float* __restrict__ o1) {
  __shared__ __align__(16) float wT[9][24];
  __shared__ float bb[24];
  int tid = threadIdx.x;
  if (tid < 216) wT[tid % 9][tid / 9] = w1[tid];
  if (tid >= 216 && tid < 240) bb[tid - 216] = b1[tid - 216];
  __syncthreads();
  int idx = blockIdx.x * 256 + tid;
  int t = idx & 511;
  int f = (idx >> 9) % 160;
  int b = idx / (160 * 512);
  float acc[24];
#pragma unroll
  for (int c = 0; c < 24; ++c) acc[c] = bb[c];
#pragma unroll
  for (int i = 0; i < 3; ++i) {
    int fi = f - 1 + i;
    if (fi < 0 || fi >= 160) continue;
#pragma unroll
    for (int j = 0; j < 3; ++j) {
      int tj = t - 1 + j;
      if (tj < 0 || tj >= 512) continue;
      float v = h0[((size_t)(b * 160 + fi) << 9) + tj];
      const float4* wr = (const float4*)&wT[i * 3 + j][0];
#pragma unroll
      for (int q = 0; q < 6; ++q) {
        float4 wv = wr[q];
        acc[q * 4 + 0] += wv.x * v; acc[q * 4 + 1] += wv.y * v;
        acc[q * 4 + 2] += wv.z * v; acc[q * 4 + 3] += wv.w * v;
      }
    }
  }
  float* dst = o1 + (size_t)idx * 24;
#pragma unroll
  for (int q = 0; q < 6; ++q) {
    float4 o;
    o.x = fmaxf(acc[q * 4 + 0], 0.f); o.y = fmaxf(acc[q * 4 + 1], 0.f);
    o.z = fmaxf(acc[q * 4 + 2], 0.f); o.w = fmaxf(acc[q * 4 + 3], 0.f);
    *(float4*)(dst + q * 4) = o;
  }
}

// ------------- RB1 conv2 + 1x1 skip + relu + maxpool(2,1) -------------------
__global__ __launch_bounds__(256) void k_rb1_rest(const float* __restrict__ o1,
                                                  const float* __restrict__ h0,
                                                  const float* __restrict__ w2,
                                                  const float* __restrict__ b2,
                                                  const float* __restrict__ wsk,
                                                  const float* __restrict__ bsk,
                                                  float* __restrict__ p1) {
  __shared__ __align__(16) float wT2[5184];
  __shared__ float bb[24], wss[24], bss[24];
  int tid = threadIdx.x;
  for (int l = tid; l < 5184; l += 256) {
    int c = l / 216, r = l % 216;
    wT2[r * 24 + c] = w2[l];
  }
  if (tid < 24) { bb[tid] = b2[tid]; wss[tid] = wsk[tid]; bss[tid] = bsk[tid]; }
  __syncthreads();
  int idx = blockIdx.x * 256 + tid;
  int t = idx & 511;
  int f2 = (idx >> 9) % 80;
  int b = idx / (80 * 512);
  float acc0[24], acc1[24];
#pragma unroll
  for (int c = 0; c < 24; ++c) { acc0[c] = bb[c]; acc1[c] = bb[c]; }
  for (int fr = 0; fr < 4; ++fr) {
    int fi = 2 * f2 - 1 + fr;
    bool fok = (fi >= 0 && fi < 160);
    for (int jr = 0; jr < 3; ++jr) {
      int tj = t - 1 + jr;
      bool ok = fok && (tj >= 0) && (tj < 512);
      float in_[24];
      if (ok) {
        const float4* src = (const float4*)(o1 + ((size_t)(b * 160 + fi) * 512 + tj) * 24);
#pragma unroll
        for (int q = 0; q < 6; ++q) {
          float4 v = src[q];
          in_[q * 4] = v.x; in_[q * 4 + 1] = v.y; in_[q * 4 + 2] = v.z; in_[q * 4 + 3] = v.w;
        }
      } else {
#pragma unroll
        for (int q = 0; q < 24; ++q) in_[q] = 0.f;
      }
      if (fr < 3) {
        int ij = fr * 3 + jr;
#pragma unroll
        for (int ci = 0; ci < 24; ++ci) {
          float iv = in_[ci];
          const float4* wr = (const float4*)&wT2[(ci * 9 + ij) * 24];
#pragma unroll
          for (int q = 0; q < 6; ++q) {
            float4 wv = wr[q];
            acc0[q * 4 + 0] += wv.x * iv; acc0[q * 4 + 1] += wv.y * iv;
            acc0[q * 4 + 2] += wv.z * iv; acc0[q * 4 + 3] += wv.w * iv;
          }
        }
      }
      if (fr >= 1) {
        int ij = (fr - 1) * 3 + jr;
#pragma unroll
        for (int ci = 0; ci < 24; ++ci) {
          float iv = in_[ci];
          const float4* wr = (const float4*)&wT2[(ci * 9 + ij) * 24];
#pragma unroll
          for (int q = 0; q < 6; ++q) {
            float4 wv = wr[q];
            acc1[q * 4 + 0] += wv.x * iv; acc1[q * 4 + 1] += wv.y * iv;
            acc1[q * 4 + 2] += wv.z * iv; acc1[q * 4 + 3] += wv.w * iv;
          }
        }
      }
    }
  }
  float h0a = h0[((size_t)(b * 160 + 2 * f2) << 9) + t];
  float h0b = h0[((size_t)(b * 160 + 2 * f2 + 1) << 9) + t];
  float* dst = p1 + (size_t)idx * 24;
#pragma unroll
  for (int q = 0; q < 6; ++q) {
    float4 o;
#pragma unroll
    for (int e = 0; e < 4; ++e) {
      int c = q * 4 + e;
      float v0 = fmaxf(acc0[c] + wss[c] * h0a + bss[c], 0.f);
      float v1 = fmaxf(acc1[c] + wss[c] * h0b + bss[c], 0.f);
      ((float*)&o)[e] = fmaxf(v0, v1);
    }
    *(float4*)(dst + q * 4) = o;
  }
}

// ---------------- RB2 conv1 (24->24, 3x3, relu) -----------------------------
__global__ __launch_bounds__(256) void k_rb2_conv1(const float* __restrict__ p1,
                                                   const float* __restrict__ w,
                                                   const float* __restrict__ bias,
                                                   float* __restrict__ o2) {
  __shared__ __align__(16) float wT[5184];
  __shared__ float bb[24];
  int tid = threadIdx.x;
  for (int l = tid; l < 5184; l += 256) {
    int c = l / 216, r = l % 216;
    wT[r * 24 + c] = w[l];
  }
  if (tid < 24) bb[tid] = bias[tid];
  __syncthreads();
  int idx = blockIdx.x * 256 + tid;
  int t = idx & 511;
  int f = (idx >> 9) % 80;
  int b = idx / (80 * 512);
  float acc[24];
#pragma unroll
  for (int c = 0; c < 24; ++c) acc[c] = bb[c];
  for (int i = 0; i < 3; ++i) {
    int fi = f - 1 + i;
    bool fok = (fi >= 0 && fi < 80);
    for (int j = 0; j < 3; ++j) {
      int tj = t - 1 + j;
      bool ok = fok && (tj >= 0) && (tj < 512);
      float in_[24];
      if (ok) {
        const float4* src = (const float4*)(p1 + ((size_t)(b * 80 + fi) * 512 + tj) * 24);
#pragma unroll
        for (int q = 0; q < 6; ++q) {
          float4 v = src[q];
          in_[q * 4] = v.x; in_[q * 4 + 1] = v.y; in_[q * 4 + 2] = v.z; in_[q * 4 + 3] = v.w;
        }
      } else {
#pragma unroll
        for (int q = 0; q < 24; ++q) in_[q] = 0.f;
      }
      int ij = i * 3 + j;
#pragma unroll
      for (int ci = 0; ci < 24; ++ci) {
        float iv = in_[ci];
        const float4* wr = (const float4*)&wT[(ci * 9 + ij) * 24];
#pragma unroll
        for (int q = 0; q < 6; ++q) {
          float4 wv = wr[q];
          acc[q * 4 + 0] += wv.x * iv; acc[q * 4 + 1] += wv.y * iv;
          acc[q * 4 + 2] += wv.z * iv; acc[q * 4 + 3] += wv.w * iv;
        }
      }
    }
  }
  float* dst = o2 + (size_t)idx * 24;
#pragma unroll
  for (int q = 0; q < 6; ++q) {
    float4 o;
    o.x = fmaxf(acc[q * 4 + 0], 0.f); o.y = fmaxf(acc[q * 4 + 1], 0.f);
    o.z = fmaxf(acc[q * 4 + 2], 0.f); o.w = fmaxf(acc[q * 4 + 3], 0.f);
    *(float4*)(dst + q * 4) = o;
  }
}

// ---- RB2 conv2 + identity skip + relu + pool + scatter to seq [b,t,960] ----
__global__ __launch_bounds__(256) void k_rb2_rest(const float* __restrict__ o2,
                                                  const float* __restrict__ p1,
                                                  const float* __restrict__ w,
                                                  const float* __restrict__ bias,
                                                  float* __restrict__ seq) {
  __shared__ __align__(16) float wT2[5184];
  __shared__ float bb[24];
  int tid = threadIdx.x;
  for (int l = tid; l < 5184; l += 256) {
    int c = l / 216, r = l % 216;
    wT2[r * 24 + c] = w[l];
  }
  if (tid < 24) bb[tid] = bias[tid];
  __syncthreads();
  int idx = blockIdx.x * 256 + tid;
  int t = idx & 511;
  int f2 = (idx >> 9) % 40;
  int b = idx / (40 * 512);
  float acc0[24], acc1[24];
#pragma unroll
  for (int c = 0; c < 24; ++c) { acc0[c] = bb[c]; acc1[c] = bb[c]; }
  for (int fr = 0; fr < 4; ++fr) {
    int fi = 2 * f2 - 1 + fr;
    bool fok = (fi >= 0 && fi < 80);
    for (int jr = 0; jr < 3; ++jr) {
      int tj = t - 1 + jr;
      bool ok = fok && (tj >= 0) && (tj < 512);
      float in_[24];
      if (ok) {
        const float4* src = (const float4*)(o2 + ((size_t)(b * 80 + fi) * 512 + tj) * 24);
#pragma unroll
        for (int q = 0; q < 6; ++q) {
          float4 v = src[q];
          in_[q * 4] = v.x; in_[q * 4 + 1] = v.y; in_[q * 4 + 2] = v.z; in_[q * 4 + 3] = v.w;
        }
      } else {
#pragma unroll
        for (int q = 0; q < 24; ++q) in_[q] = 0.f;
      }
      if (fr < 3) {
        int ij = fr * 3 + jr;
#pragma unroll
        for (int ci = 0; ci < 24; ++ci) {
          float iv = in_[ci];
          const float4* wr = (const float4*)&wT2[(ci * 9 + ij) * 24];
#pragma unroll
          for (int q = 0; q < 6; ++q) {
            float4 wv = wr[q];
            acc0[q * 4 + 0] += wv.x * iv; acc0[q * 4 + 1] += wv.y * iv;
            acc0[q * 4 + 2] += wv.z * iv; acc0[q * 4 + 3] += wv.w * iv;
          }
        }
      }
      if (fr >= 1) {
        int ij = (fr - 1) * 3 + jr;
#pragma unroll
        for (int ci = 0; ci < 24; ++ci) {
          float iv = in_[ci];
          const float4* wr = (const float4*)&wT2[(ci * 9 + ij) * 24];
#pragma unroll
          for (int q = 0; q < 6; ++q) {
            float4 wv = wr[q];
            acc1[q * 4 + 0] += wv.x * iv; acc1[q * 4 + 1] += wv.y * iv;
            acc1[q * 4 + 2] += wv.z * iv; acc1[q * 4 + 3] += wv.w * iv;
          }
        }
      }
    }
  }
  const float* s0p = p1 + ((size_t)(b * 80 + 2 * f2) * 512 + t) * 24;
  const float* s1p = p1 + ((size_t)(b * 80 + 2 * f2 + 1) * 512 + t) * 24;
  float* srow = seq + (size_t)(b * 512 + t) * 960 + f2;
#pragma unroll
  for (int c = 0; c < 24; ++c) {
    float v0 = fmaxf(acc0[c] + s0p[c], 0.f);
    float v1 = fmaxf(acc1[c] + s1p[c], 0.f);
    srow[c * 40] = fmaxf(v0, v1);
  }
}

// ---- SGEMM 64(M)x128(N), double-buffered LDS, optional split-K partials ----
// C[M,N] = A[M,K] * B[N,K]^T over K-chunk [bz*kchunk, min(..+kchunk,K));
// partial bz written to C + bz*partStride (partStride=0 => single full pass).
__global__ __launch_bounds__(256) void k_sgemm_nt_db(const float* __restrict__ A,
                                                     const float* __restrict__ B,
                                                     float* __restrict__ C,
                                                     int M, int N, int K,
                                                     int kchunk, int partStride) {
  __shared__ __align__(16) float As[2][16][68];
  __shared__ __align__(16) float Bs[2][16][132];
  int tid = threadIdx.x;
  int lra = tid >> 2;           // 0..63   A tile row
  int lka = (tid & 3) * 4;      // 0,4,8,12
  int lrb = tid >> 1;           // 0..127  B tile row
  int lkb = (tid & 1) * 8;      // 0 or 8
  int tm = (tid >> 4) * 4;      // 0..60
  int tn = (tid & 15) * 4;      // 0..60
  int bm = blockIdx.y * 64, bn = blockIdx.x * 128;
  int kbeg = blockIdx.z * kchunk;
  int kend = kbeg + kchunk; if (kend > K) kend = K;
  int S = (kend - kbeg) >> 4;   // K-steps of 16
  bool bok = (bn + lrb) < N;
  const float* Ap = A + (size_t)(bm + lra) * K + kbeg + lka;
  const float* Bp = B + (size_t)(bok ? (bn + lrb) : 0) * K + kbeg + lkb;
  float* Cp = C + (size_t)blockIdx.z * partStride;

  float acc[4][8];
#pragma unroll
  for (int i = 0; i < 4; ++i)
#pragma unroll
    for (int j = 0; j < 8; ++j) acc[i][j] = 0.f;
  float4 z4 = make_float4(0.f, 0.f, 0.f, 0.f);

  // prologue: stage tile 0 into buffer 0
  float4 a4 = *(const float4*)(Ap);
  float4 b4 = bok ? *(const float4*)(Bp) : z4;
  float4 b4b = bok ? *(const float4*)(Bp + 4) : z4;
  As[0][lka + 0][lra] = a4.x; As[0][lka + 1][lra] = a4.y;
  As[0][lka + 2][lra] = a4.z; As[0][lka + 3][lra] = a4.w;
  Bs[0][lkb + 0][lrb] = b4.x;  Bs[0][lkb + 1][lrb] = b4.y;
  Bs[0][lkb + 2][lrb] = b4.z;  Bs[0][lkb + 3][lrb] = b4.w;
  Bs[0][lkb + 4][lrb] = b4b.x; Bs[0][lkb + 5][lrb] = b4b.y;
  Bs[0][lkb + 6][lrb] = b4b.z; Bs[0][lkb + 7][lrb] = b4b.w;
  __syncthreads();

  int p = 0;
  for (int s = 0; s < S; ++s) {
    bool more = (s + 1 < S);
    if (more) {
      int ko = (s + 1) << 4;
      a4  = *(const float4*)(Ap + ko);
      b4  = bok ? *(const float4*)(Bp + ko) : z4;
      b4b = bok ? *(const float4*)(Bp + ko + 4) : z4;
    }
#pragma unroll
    for (int kk = 0; kk < 16; ++kk) {
      float4 a0 = *(const float4*)&As[p][kk][tm];
      float4 b0 = *(const float4*)&Bs[p][kk][tn];
      float4 b1 = *(const float4*)&Bs[p][kk][tn + 64];
      float am[4] = {a0.x, a0.y, a0.z, a0.w};
      float bv[8] = {b0.x, b0.y, b0.z, b0.w, b1.x, b1.y, b1.z, b1.w};
#pragma unroll
      for (int i = 0; i < 4; ++i)
#pragma unroll
        for (int j = 0; j < 8; ++j) acc[i][j] += am[i] * bv[j];
    }
    if (more) {
      int q = p ^ 1;
      As[q][lka + 0][lra] = a4.x; As[q][lka + 1][lra] = a4.y;
      As[q][lka + 2][lra] = a4.z; As[q][lka + 3][lra] = a4.w;
      Bs[q][lkb + 0][lrb] = b4.x;  Bs[q][lkb + 1][lrb] = b4.y;
      Bs[q][lkb + 2][lrb] = b4.z;  Bs[q][lkb + 3][lrb] = b4.w;
      Bs[q][lkb + 4][lrb] = b4b.x; Bs[q][lkb + 5][lrb] = b4b.y;
      Bs[q][lkb + 6][lrb] = b4b.z; Bs[q][lkb + 7][lrb] = b4b.w;
    }
    __syncthreads();
    p ^= 1;
  }

#pragma unroll
  for (int i = 0; i < 4; ++i) {
    int row = bm + tm + i;
#pragma unroll
    for (int jh = 0; jh < 2; ++jh) {
      int col = bn + jh * 64 + tn;
      if (col < N) {
        float4 o = make_float4(acc[i][jh * 4 + 0], acc[i][jh * 4 + 1],
                               acc[i][jh * 4 + 2], acc[i][jh * 4 + 3]);
        *(float4*)&Cp[(size_t)row * N + col] = o;
      }
    }
  }
}

// ---------------- causal depthwise conv1d + silu ----------------------------
__global__ __launch_bounds__(256) void k_conv1d_silu(const float* __restrict__ xz,
                                                     const float* __restrict__ cw,
                                                     const float* __restrict__ cb,
                                                     float* __restrict__ xc) {
  int idx = blockIdx.x * 256 + threadIdx.x;
  int d = idx % DI;
  int m = idx / DI;
  int t = m & 511;
  int b = m >> 9;
  float4 w4 = *(const float4*)(cw + (size_t)d * 4);
  const float* xin = xz + (size_t)(b * 512) * (2 * DI) + d;
  float s = cb[d];
  if (t >= 3) s += w4.x * xin[(size_t)(t - 3) * (2 * DI)];
  if (t >= 2) s += w4.y * xin[(size_t)(t - 2) * (2 * DI)];
  if (t >= 1) s += w4.z * xin[(size_t)(t - 1) * (2 * DI)];
  s += w4.w * xin[(size_t)t * (2 * DI)];
  xc[idx] = s / (1.f + __expf(-s));
}

// ---- x_proj v2: wave-cooperative dots, coalesced weight reads --------------
// Block: 4 seq-rows staged in LDS; wave w handles j = w*23 .. w*23+22.
// Lane l sums k = l, l+64, ... (xw reads coalesced); shuffle-reduce per dot.
__global__ __launch_bounds__(256) void k_xproj2(const float* __restrict__ xc,
                                                const float* __restrict__ xw,
                                                float* __restrict__ dbc) {
  __shared__ float xcl[4 * DI];
  int tid = threadIdx.x;
  int m0 = blockIdx.x * 4;                       // grid 512
  for (int i = tid; i < 4 * DI; i += 256)
    xcl[i] = xc[(size_t)m0 * DI + i];
  __syncthreads();
  int wv = tid >> 6, l = tid & 63;
  for (int jj = 0; jj < 23; ++jj) {
    int j = wv * 23 + jj;
    const float* wrow = xw + (size_t)j * DI;
    float s0 = 0.f, s1 = 0.f, s2 = 0.f, s3 = 0.f;
    for (int it = 0; it < DI / 64; ++it) {
      int k = l + it * 64;
      float wvv = wrow[k];
      s0 += xcl[k] * wvv;
      s1 += xcl[DI + k] * wvv;
      s2 += xcl[2 * DI + k] * wvv;
      s3 += xcl[3 * DI + k] * wvv;
    }
#pragma unroll
    for (int o = 32; o > 0; o >>= 1) {
      s0 += __shfl_xor(s0, o, 64);
      s1 += __shfl_xor(s1, o, 64);
      s2 += __shfl_xor(s2, o, 64);
      s3 += __shfl_xor(s3, o, 64);
    }
    if (l == 0) {
      dbc[(size_t)(m0 + 0) * 92 + j] = s0;
      dbc[(size_t)(m0 + 1) * 92 + j] = s1;
      dbc[(size_t)(m0 + 2) * 92 + j] = s2;
      dbc[(size_t)(m0 + 3) * 92 + j] = s3;
    }
  }
}

// ---- dt_proj v2 + softplus: LDS-staged weights, coalesced ------------------
// Block: n-chunk of 256 (n = n0+tid), m-chunk of 32. dtw chunk in LDS
// (pad 61 -> 2-way-free banks); dbc rows read as uniform float4 broadcasts.
__global__ __launch_bounds__(256) void k_dtproj2(const float* __restrict__ dbc,
                                                 const float* __restrict__ dtw,
                                                 const float* __restrict__ dtb,
                                                 float* __restrict__ dt) {
  __shared__ float wl[256 * 61];
  __shared__ float bl[256];
  int tid = threadIdx.x;
  int n0 = blockIdx.x * 256;                     // grid (8, 64)
  int m0 = blockIdx.y * 32;
  int nv = DI - n0; if (nv > 256) nv = 256;
  for (int f = tid; f < nv * 60; f += 256)
    wl[(f / 60) * 61 + (f % 60)] = dtw[(size_t)n0 * 60 + f];
  if (tid < nv) bl[tid] = dtb[n0 + tid];
  __syncthreads();
  bool valid = tid < nv;
  int n = n0 + tid;
  const float* wrow = &wl[tid * 61];
  for (int mi = 0; mi < 32; ++mi) {
    int m = m0 + mi;
    const float4* dr = (const float4*)(dbc + (size_t)m * 92);
    float s = valid ? bl[tid] : 0.f;
#pragma unroll
    for (int q = 0; q < 15; ++q) {
      float4 d4 = dr[q];
      s += d4.x * wrow[q * 4 + 0] + d4.y * wrow[q * 4 + 1] +
           d4.z * wrow[q * 4 + 2] + d4.w * wrow[q * 4 + 3];
    }
    float sp = (s > 20.f) ? s : log1pf(__expf(s));
    if (valid) dt[(size_t)m * DI + n] = sp;
  }
}

// ------ selective scan v2: block-parallel chunked scan over time ------------
__global__ __launch_bounds__(256) void k_scan2(const float* __restrict__ dt,
                                               const float* __restrict__ xc,
                                               const float* __restrict__ dbc,
                                               const float* __restrict__ xz,
                                               const float* __restrict__ A_log,
                                               const float* __restrict__ Dp,
                                               float* __restrict__ y) {
  int tid = threadIdx.x;
  int n = tid & 15, sg = tid >> 4;
  int blk = blockIdx.x;                          // 4*1920 = 7680
  int b = blk / DI;
  int d = blk % DI;
  float a = -__expf(A_log[(size_t)d * NST + n]);
  float dpv = Dp[d];
  size_t base = (size_t)b * 512 + sg * 32;

  __shared__ float sH[16][16];
  __shared__ float sP[16][16];
  __shared__ float sI[16][16];

  float h = 0.f, sdt = 0.f;
#pragma unroll 4
  for (int j = 0; j < 32; ++j) {
    size_t m = base + j;
    float c_dt = dt[m * DI + d];
    float c_u  = xc[m * DI + d];
    float c_B  = dbc[m * 92 + 60 + n];
    float dA = __expf(c_dt * a);
    h = dA * h + c_dt * c_B * c_u;
    sdt += c_dt;
  }
  sH[sg][n] = h;
  sP[sg][n] = __expf(sdt * a);
  __syncthreads();

  if (sg == 0) {
    float E = 0.f;
#pragma unroll
    for (int s = 0; s < 16; ++s) {
      sI[s][n] = E;
      E = sH[s][n] + sP[s][n] * E;
    }
  }
  __syncthreads();

  h = sI[sg][n];
#pragma unroll 4
  for (int j = 0; j < 32; ++j) {
    size_t m = base + j;
    float c_dt = dt[m * DI + d];
    float c_u  = xc[m * DI + d];
    float c_B  = dbc[m * 92 + 60 + n];
    float c_C  = dbc[m * 92 + 76 + n];
    float dA = __expf(c_dt * a);
    h = dA * h + c_dt * c_B * c_u;
    float pv = h * c_C;
    pv += __shfl_xor(pv, 1, 16);
    pv += __shfl_xor(pv, 2, 16);
    pv += __shfl_xor(pv, 4, 16);
    pv += __shfl_xor(pv, 8, 16);
    if (n == 0) {
      float c_z = xz[m * (2 * DI) + DI + d];
      float sgate = c_z / (1.f + __expf(-c_z));
      y[m * DI + d] = (pv + c_u * dpv) * sgate;
    }
  }
}

// ------- residual add (4 split-K partials) + rmsnorm (in-place on seq) ------
__global__ __launch_bounds__(256) void k_addnorm4(float* __restrict__ seq,
                                                  const float* __restrict__ res4,
                                                  const float* __restrict__ w) {
  int row = blockIdx.x;
  int tid = threadIdx.x;
  __shared__ float red[4];
  float v[4];
  float ss = 0.f;
#pragma unroll
  for (int q = 0; q < 4; ++q) {
    int j = tid + q * 256;
    if (j < 960) {
      size_t o = (size_t)row * 960 + j;
      float x = seq[o] + res4[o] + res4[o + PSTRIDE] +
                res4[o + 2 * (size_t)PSTRIDE] + res4[o + 3 * (size_t)PSTRIDE];
      v[q] = x;
      ss += x * x;
    } else v[q] = 0.f;
  }
#pragma unroll
  for (int o = 32; o > 0; o >>= 1) ss += __shfl_xor(ss, o, 64);
  if ((tid & 63) == 0) red[tid >> 6] = ss;
  __syncthreads();
  ss = red[0] + red[1] + red[2] + red[3];
  float rs = rsqrtf(ss / 960.f + 1e-5f);
#pragma unroll
  for (int q = 0; q < 4; ++q) {
    int j = tid + q * 256;
    if (j < 960) seq[(size_t)row * 960 + j] = v[q] * rs * w[j];
  }
}

// ---------------- final fc + relu + transpose to [B,10,T] -------------------
__global__ __launch_bounds__(256) void k_fc(const float* __restrict__ seq,
                                            const float* __restrict__ fw,
                                            const float* __restrict__ fb,
                                            float* __restrict__ out) {
  int idx = blockIdx.x * 256 + threadIdx.x;
  int m = idx >> 4, c = idx & 15;
  if (c >= 10) return;
  const float4* a = (const float4*)(seq + (size_t)m * 960);
  const float4* w = (const float4*)(fw + (size_t)c * 960);
  float s = fb[c];
#pragma unroll 8
  for (int k = 0; k < 240; ++k) {
    float4 av = a[k], wv = w[k];
    s += av.x * wv.x + av.y * wv.y + av.z * wv.z + av.w * wv.w;
  }
  int b = m >> 9, t = m & 511;
  out[(size_t)(b * 10 + c) * 512 + t] = fmaxf(s, 0.f);
}

// ---------------------------------------------------------------------------
extern "C" void kernel_launch(void* const* d_in, const int* in_sizes, int n_in,
                              void* d_out, int out_size, void* d_ws, size_t ws_size,
                              hipStream_t stream) {
  const float* x       = (const float*)d_in[0];
  const float* cb1_w1  = (const float*)d_in[1];
  const float* cb1_b1  = (const float*)d_in[2];
  const float* cb1_w2  = (const float*)d_in[3];
  const float* cb1_b2  = (const float*)d_in[4];
  const float* cb1_ws  = (const float*)d_in[5];
  const float* cb1_bs  = (const float*)d_in[6];
  const float* cb2_w1  = (const float*)d_in[7];
  const float* cb2_b1  = (const float*)d_in[8];
  const float* cb2_w2  = (const float*)d_in[9];
  const float* cb2_b2  = (const float*)d_in[10];
  const float* in_proj = (const float*)d_in[11];
  const float* c1d_w   = (const float*)d_in[12];
  const float* c1d_b   = (const float*)d_in[13];
  const float* xp_w    = (const float*)d_in[14];
  const float* dtp_w   = (const float*)d_in[15];
  const float* dtp_b   = (const float*)d_in[16];
  const float* A_log   = (const float*)d_in[17];
  const float* D_par   = (const float*)d_in[18];
  const float* op_w    = (const float*)d_in[19];
  const float* nw      = (const float*)d_in[20];
  const float* fc_w    = (const float*)d_in[21];
  const float* fc_b    = (const float*)d_in[22];

  float* W = (float*)d_ws;
  // CNN phase: h0,o1,p1,o2,seq live.  Mamba phase: xz(=o1, dead after scan2
  // -> reused as res4 partials), xc(=p1), dt(=o2), dbc(=h0), seq, yb.
  float* h0  = W;                     //   327,680
  float* o1  = W + 327680;            // 7,864,320  (xz; then res4[4] partials)
  float* p1  = W + 8192000;           // 3,932,160  (xc)
  float* o2  = W + 12124160;          // 3,932,160  (dt)
  float* seq = W + 16056320;          // 1,966,080
  float* yb  = W + 18022400;          // 3,932,160
  float* xz  = o1;
  float* xc  = p1;
  float* dtb = o2;
  float* dbc = h0;
  float* res4 = o1;                   // 4 partials x 1,966,080 = 7,864,320 ✓

  // CNN front-end
  k_flux<<<1280, 256, 0, stream>>>(x, h0);
  k_rb1_conv1<<<1280, 256, 0, stream>>>(h0, cb1_w1, cb1_b1, o1);
  k_rb1_rest<<<640, 256, 0, stream>>>(o1, h0, cb1_w2, cb1_b2, cb1_ws, cb1_bs, p1);
  k_rb2_conv1<<<640, 256, 0, stream>>>(p1, cb2_w1, cb2_b1, o2);
  k_rb2_rest<<<320, 256, 0, stream>>>(o2, p1, cb2_w2, cb2_b2, seq);

  // Mamba layers
  for (int i = 0; i < 3; ++i) {
    // in_proj: 2048x3840x960, 64x128 tiles, full K
    k_sgemm_nt_db<<<dim3(30, 32, 1), 256, 0, stream>>>(
        seq, in_proj + (size_t)i * 2 * DI * DM, xz, 2048, 2 * DI, DM, DM, 0);
    k_conv1d_silu<<<15360, 256, 0, stream>>>(
        xz, c1d_w + (size_t)i * DI * 4, c1d_b + (size_t)i * DI, xc);
    k_xproj2<<<512, 256, 0, stream>>>(xc, xp_w + (size_t)i * 92 * DI, dbc);
    k_dtproj2<<<dim3(8, 64), 256, 0, stream>>>(
        dbc, dtp_w + (size_t)i * DI * DTR, dtp_b + (size_t)i * DI, dtb);
    k_scan2<<<7680, 256, 0, stream>>>(
        dtb, xc, dbc, xz, A_log + (size_t)i * DI * NST, D_par + (size_t)i * DI, yb);
    // out_proj: 2048x960x1920, split-K x4 into res4 partials (xz now dead)
    k_sgemm_nt_db<<<dim3(8, 32, 4), 256, 0, stream>>>(
        yb, op_w + (size_t)i * DM * DI, res4, 2048, DM, DI, 480, PSTRIDE);
    k_addnorm4<<<2048, 256, 0, stream>>>(seq, res4, nw + (size_t)i * DM);
  }
  k_fc<<<128, 256, 0, stream>>>(seq, fc_w, fc_b, (float*)d_out);
}